// Round 6
// baseline (287.318 us; speedup 1.0000x reference)
//
#include <hip/hip_runtime.h>

// Problem constants
#define NB 16
#define CC 512
#define WW 4096
#define FD 512
#define NMASK 1024          // NUM_MASKS * MASK_WIDTH
#define T_COMB 11264        // 1024 masked + 10240 negative rows
#define OUT0_ELEMS (NB*CC*WW)   // 33554432 floats

// Workspace layout (bytes):
//   [0, 256KB)           : int32 lookup[N*W]  (flat pos -> combined row g, or -1)
//   [256KB, 768KB)       : bf16 Wq  [512][512]
//   [768KB, ~12.3MB)     : bf16 A   [11264][512]
#define WS_LOOKUP_OFF 0
#define WS_WQ_OFF     262144
#define WS_A_OFF      786432

#define S_LDS 36            // ushort stride per c-row in the transpose tile

typedef __attribute__((ext_vector_type(8))) short short8;
typedef __attribute__((ext_vector_type(4))) float f32x4;
typedef __attribute__((ext_vector_type(4))) unsigned short u16x4;

__device__ __forceinline__ unsigned short f2bf(float x) {
  unsigned int u = __builtin_bit_cast(unsigned int, x);
  u += 0x7fffu + ((u >> 16) & 1u);   // round-to-nearest-even
  return (unsigned short)(u >> 16);
}

__device__ __forceinline__ void gload_lds16(const void* gp, void* lp) {
  __builtin_amdgcn_global_load_lds(
      (__attribute__((address_space(1))) void*)(gp),
      (__attribute__((address_space(3))) void*)(lp),
      16, 0, 0);
}

// K0: scatter combined row ids into the (memset to -1) lookup table
// (blocks 0..43) + Wq fp32->bf16 conversion (blocks 44..107; independent of
// lookup, moved here so it doesn't tail behind the 2048-block copy).
__global__ __launch_bounds__(256) void scatter_wq_k(
    const int* __restrict__ pack_idx, const int* __restrict__ masked_idx,
    const int* __restrict__ neg_idx, int* __restrict__ lookup,
    const float* __restrict__ Wq, unsigned short* __restrict__ Wq_ws) {
  const int bx = blockIdx.x;
  const int tid = threadIdx.x;
  if (bx < 44) {
    int g = bx * 256 + tid;                        // [0, 11264)
    int pidx = (g < NMASK) ? masked_idx[g] : neg_idx[g - NMASK];
    lookup[pack_idx[pidx]] = g;
    return;
  }
  // Wq: 262144 elems = 65536 float4 over 64 blocks
  int b2 = bx - 44;
  const f32x4* wq4 = (const f32x4*)Wq;
#pragma unroll
  for (int it = 0; it < 4; ++it) {
    int i4 = it * 16384 + b2 * 256 + tid;
    f32x4 v = wq4[i4];
    u16x4 o;
    o[0] = f2bf(v[0]); o[1] = f2bf(v[1]); o[2] = f2bf(v[2]); o[3] = f2bf(v[3]);
    ((u16x4*)Wq_ws)[i4] = o;
  }
}

// K1: tile-transpose streaming copy. Block = (n, all c, 32 w).
// seq_len is a multiple of 128, tiles are 32-wide -> each tile is all-valid
// or all-invalid. Invalid: pure zero-fill (no reads). Valid: coalesced
// nontemporal in-read + out0 write (mask path gated by wave-uniform ballot),
// bf16 pre-mask values into padded LDS tile [c][w] only when the tile holds
// selected (masked/negative) slots; phase 2 emits A rows coalesced.
__global__ __launch_bounds__(256) void fused_copy_k(
    const float* __restrict__ in, const int* __restrict__ seq_len,
    const int* __restrict__ lookup, const float* __restrict__ mask_emb,
    float* __restrict__ out0, unsigned short* __restrict__ A_ws) {
  const int tid = threadIdx.x;
  const int bx = blockIdx.x;
  const int n = bx >> 7;                 // 16 n-lines
  const int w0 = (bx & 127) * 32;        // 128 w-tiles per line
  const int wl4 = (tid & 7) * 4;         // this thread's 4-w slot
  const int w = w0 + wl4;
  const int c0 = tid >> 3;               // 0..31
  const size_t rowbase = ((size_t)n << 21) + (size_t)w;   // element index
  f32x4* out4 = (f32x4*)out0;
  const int L = seq_len[n];

  if (w0 + 32 > L) {
    // fully-invalid tile: zero-fill out0, nothing else to do
    f32x4 z = {0.f, 0.f, 0.f, 0.f};
#pragma unroll
    for (int it = 0; it < 16; ++it) {
      int c = it * 32 + c0;
      __builtin_nontemporal_store(z, &out4[(rowbase + ((size_t)c << 12)) >> 2]);
    }
    return;
  }

  __shared__ unsigned short tile[CC * S_LDS];   // 36 KB
  __shared__ int g_s[32];
  if (tid < 32) g_s[tid] = lookup[n * WW + w0 + tid];

  const int4 g4 = *(const int4*)&lookup[n * WW + w];   // 16B aligned
  const int gg[4] = {g4.x, g4.y, g4.z, g4.w};
  bool lane_has_mask = ((unsigned)gg[0] < (unsigned)NMASK) |
                       ((unsigned)gg[1] < (unsigned)NMASK) |
                       ((unsigned)gg[2] < (unsigned)NMASK) |
                       ((unsigned)gg[3] < (unsigned)NMASK);
  bool lane_has_sel = (gg[0] >= 0) | (gg[1] >= 0) | (gg[2] >= 0) | (gg[3] >= 0);
  // every wave contains all 8 w4-groups (gg depends only on wl4), so the
  // ballot outcome is identical across the block's 4 waves -> block-uniform.
  bool has_mask = __ballot(lane_has_mask) != 0ull;
  bool has_sel = __ballot(lane_has_sel) != 0ull;   // superset of has_mask

  const f32x4* in4 = (const f32x4*)in;
#pragma unroll
  for (int it = 0; it < 16; ++it) {
    int c = it * 32 + c0;
    size_t i4 = (rowbase + ((size_t)c << 12)) >> 2;
    f32x4 v = __builtin_nontemporal_load(&in4[i4]);
    if (has_sel) {   // wave-uniform: stage pre-mask bf16 values for A emission
      u16x4 bf;
      bf[0] = f2bf(v[0]); bf[1] = f2bf(v[1]);
      bf[2] = f2bf(v[2]); bf[3] = f2bf(v[3]);
      *(u16x4*)&tile[c * S_LDS + wl4] = bf;
    }
    if (has_mask) {   // wave-uniform branch
      float o[4] = {v[0], v[1], v[2], v[3]};
#pragma unroll
      for (int k = 0; k < 4; ++k)
        if ((unsigned)gg[k] < (unsigned)NMASK)
          o[k] = mask_emb[(gg[k] & 3) * CC + c];
      v[0] = o[0]; v[1] = o[1]; v[2] = o[2]; v[3] = o[3];
    }
    __builtin_nontemporal_store(v, &out4[i4]);
  }
  if (!has_sel) return;    // block-uniform: no A rows from this tile
  __syncthreads();

  // Phase 2: coalesced A-row emission over selected slots only.
  const int lane = tid & 63;
  bool sel = (lane < 32) && (g_s[lane & 31] >= 0);
  unsigned smask = (unsigned)__ballot(sel);
  const int c2 = tid * 2;
  while (smask) {
    int wl = __builtin_ctz(smask);
    smask &= smask - 1;
    int g = g_s[wl];
    ushort2 val;
    val.x = tile[c2 * S_LDS + wl];
    val.y = tile[(c2 + 1) * S_LDS + wl];
    *(ushort2*)&A_ws[(size_t)g * CC + c2] = val;
  }
}

// K2: bf16 MFMA GEMM  out[m,f] = sum_c A[m,c]*Wq[f,c] + bq[f]
// M=11264, N=512, K=512.  64x128 block tile, 4 waves (2x2), 2x4 16x16
// frags/wave.  BK=32, FOUR LDS buffers (48 KB total -> 3 blocks/CU kept),
// counted-vmcnt pipeline (T3+T4): 3 stages in flight, per-iter wait is
// s_waitcnt vmcnt(6) (2 younger stages x 3 loads stay in flight) + raw
// s_barrier — the stage queue NEVER drains to 0 in steady state, unlike the
// old 2-buffer/full-drain loop.  Epilogue ladder vmcnt(3) -> vmcnt(0).
// Per-thread wait + barrier = block-wide readiness (each thread's own 3
// stage-t loads retire before the join).  WAR: stage(t+3) overwrites the
// buffer read at t-1, issued after the t-1 barrier.
// LDS chunk-index XOR-swizzle on BOTH sides (rule #21): 4 chunks/row,
// physical chunk = logical ^ (row&3).
__global__ __launch_bounds__(256) void gemm_k(
    const unsigned short* __restrict__ A, const unsigned short* __restrict__ B,
    const float* __restrict__ bq, float* __restrict__ out) {
  __shared__ unsigned short As[4][64 * 32];     // 4 x 4 KB
  __shared__ unsigned short Bs[4][128 * 32];    // 4 x 8 KB
  const int tid = threadIdx.x;
  const int lane = tid & 63;
  const int quad = lane >> 4;
  const int r16 = lane & 15;
  const int wv = tid >> 6;
  // bijective id -> (x, y): x = (id&7) + 8*(id>>5), y = (id>>3)&3
  const int id = blockIdx.x;
  const int xm = (id & 7) + ((id >> 5) << 3);   // [0, 176)
  const int yn = (id >> 3) & 3;                 // [0, 4)
  const int bm = xm * 64;
  const int bf = yn * 128;
  const int wm = (wv & 1) * 32;
  const int wf = (wv >> 1) * 64;
  const int wbase = tid & ~63;   // wave-uniform

  f32x4 acc[2][4];
#pragma unroll
  for (int mi = 0; mi < 2; ++mi)
#pragma unroll
    for (int fi = 0; fi < 4; ++fi)
      acc[mi][fi] = (f32x4){0.f, 0.f, 0.f, 0.f};

  // ---- staging (BK=32): A tile 64x32 = 256 16B-chunks (1/thread),
  //                        B tile 128x32 = 512 chunks (2/thread) = 3 loads.
  // LDS dest linear (chunk ch at byte ch*16); global source for physical
  // chunk p of row r fetches logical chunk (p ^ (r&3)).
#define STAGE(buf, k0)                                                        \
  do {                                                                        \
    {                                                                         \
      int row = tid >> 2;                                                     \
      int l = (tid & 3) ^ (row & 3);                                          \
      gload_lds16(A + (size_t)(bm + row) * 512 + (k0) + l * 8,                \
                  &As[buf][wbase * 8]);                                       \
    }                                                                         \
    _Pragma("unroll")                                                         \
    for (int it = 0; it < 2; ++it) {                                          \
      int ch = it * 256 + tid;                                                \
      int row = ch >> 2;                                                      \
      int l = (ch & 3) ^ (row & 3);                                           \
      gload_lds16(B + (size_t)(bf + row) * 512 + (k0) + l * 8,                \
                  &Bs[buf][(it * 256 + wbase) * 8]);                          \
    }                                                                         \
  } while (0)

  STAGE(0, 0);
  STAGE(1, 32);
  STAGE(2, 64);
  asm volatile("s_waitcnt vmcnt(6)" ::: "memory");   // stage 0 complete
  __builtin_amdgcn_s_barrier();

#pragma unroll
  for (int t = 0; t < 16; ++t) {
    if (t < 13) STAGE((t + 3) & 3, (t + 3) * 32);

    short8 a[2], b[4];
#pragma unroll
    for (int mi = 0; mi < 2; ++mi) {
      int row = wm + mi * 16 + r16;
      a[mi] = *(const short8*)&As[t & 3][row * 32 + ((quad ^ (row & 3)) << 3)];
    }
#pragma unroll
    for (int fi = 0; fi < 4; ++fi) {
      int row = wf + fi * 16 + r16;
      b[fi] = *(const short8*)&Bs[t & 3][row * 32 + ((quad ^ (row & 3)) << 3)];
    }
#pragma unroll
    for (int mi = 0; mi < 2; ++mi)
#pragma unroll
      for (int fi = 0; fi < 4; ++fi)
        acc[mi][fi] = __builtin_amdgcn_mfma_f32_16x16x32_bf16(
            a[mi], b[fi], acc[mi][fi], 0, 0, 0);

    // readiness wait for buffer (t+1)&3, then join all waves.
    if (t < 13) {
      asm volatile("s_waitcnt vmcnt(6)" ::: "memory");
    } else if (t == 13) {
      asm volatile("s_waitcnt vmcnt(3)" ::: "memory");
    } else if (t == 14) {
      asm volatile("s_waitcnt vmcnt(0)" ::: "memory");
    }
    if (t < 15) __builtin_amdgcn_s_barrier();
  }
#undef STAGE

  // Epilogue: C/D layout col = lane&15 (f), row = quad*4 + reg (m).
#pragma unroll
  for (int fi = 0; fi < 4; ++fi) {
    int f = bf + wf + fi * 16 + r16;
    float bqv = bq[f];
#pragma unroll
    for (int mi = 0; mi < 2; ++mi) {
      int m0 = bm + wm + mi * 16 + quad * 4;
#pragma unroll
      for (int r = 0; r < 4; ++r)
        __builtin_nontemporal_store(acc[mi][fi][r] + bqv,
                                    &out[(size_t)(m0 + r) * 512 + f]);
    }
  }
}

extern "C" void kernel_launch(void* const* d_in, const int* in_sizes, int n_in,
                              void* d_out, int out_size, void* d_ws, size_t ws_size,
                              hipStream_t stream) {
  const float* inputs    = (const float*)d_in[0];
  const int*   seq_len   = (const int*)d_in[1];
  const int*   pack_idx  = (const int*)d_in[2];
  const int*   masked_idx= (const int*)d_in[3];
  const int*   neg_idx   = (const int*)d_in[4];
  const float* mask_emb  = (const float*)d_in[5];
  const float* Wq        = (const float*)d_in[6];
  const float* bq        = (const float*)d_in[7];
  float* out = (float*)d_out;
  char* ws = (char*)d_ws;
  int* lookup = (int*)(ws + WS_LOOKUP_OFF);
  unsigned short* wqb = (unsigned short*)(ws + WS_WQ_OFF);
  unsigned short* aws = (unsigned short*)(ws + WS_A_OFF);

  (void)hipMemsetAsync(lookup, 0xFF, NB * WW * sizeof(int), stream);  // all -1
  scatter_wq_k<<<108, 256, 0, stream>>>(pack_idx, masked_idx, neg_idx, lookup,
                                        Wq, wqb);
  fused_copy_k<<<2048, 256, 0, stream>>>(inputs, seq_len, lookup, mask_emb,
                                         out, aws);
  gemm_k<<<704, 256, 0, stream>>>(aws, wqb, bq, out + OUT0_ELEMS);
}

// Round 7
// 284.560 us; speedup vs baseline: 1.0097x; 1.0097x over previous
//
#include <hip/hip_runtime.h>

// Problem constants
#define NB 16
#define CC 512
#define WW 4096
#define FD 512
#define NMASK 1024          // NUM_MASKS * MASK_WIDTH
#define T_COMB 11264        // 1024 masked + 10240 negative rows
#define OUT0_ELEMS (NB*CC*WW)   // 33554432 floats

// Workspace layout (bytes):
//   [0, 256KB)           : int32 lookup[N*W]  (flat pos -> combined row g, or -1)
//   [256KB, 768KB)       : bf16 Wq  [512][512]
//   [768KB, ~12.3MB)     : bf16 A   [11264][512]
#define WS_LOOKUP_OFF 0
#define WS_WQ_OFF     262144
#define WS_A_OFF      786432

#define S_LDS 36            // ushort stride per c-row in the transpose tile

typedef __attribute__((ext_vector_type(8))) short short8;
typedef __attribute__((ext_vector_type(4))) float f32x4;
typedef __attribute__((ext_vector_type(4))) unsigned short u16x4;

__device__ __forceinline__ unsigned short f2bf(float x) {
  unsigned int u = __builtin_bit_cast(unsigned int, x);
  u += 0x7fffu + ((u >> 16) & 1u);   // round-to-nearest-even
  return (unsigned short)(u >> 16);
}

__device__ __forceinline__ void gload_lds16(const void* gp, void* lp) {
  __builtin_amdgcn_global_load_lds(
      (__attribute__((address_space(1))) void*)(gp),
      (__attribute__((address_space(3))) void*)(lp),
      16, 0, 0);
}

// K0: scatter combined row ids into the (memset to -1) lookup table
// (blocks 0..43) + Wq fp32->bf16 conversion (blocks 44..107; independent of
// lookup, rides this launch so it doesn't tail behind the 2048-block copy).
__global__ __launch_bounds__(256) void scatter_wq_k(
    const int* __restrict__ pack_idx, const int* __restrict__ masked_idx,
    const int* __restrict__ neg_idx, int* __restrict__ lookup,
    const float* __restrict__ Wq, unsigned short* __restrict__ Wq_ws) {
  const int bx = blockIdx.x;
  const int tid = threadIdx.x;
  if (bx < 44) {
    int g = bx * 256 + tid;                        // [0, 11264)
    int pidx = (g < NMASK) ? masked_idx[g] : neg_idx[g - NMASK];
    lookup[pack_idx[pidx]] = g;
    return;
  }
  // Wq: 262144 elems = 65536 float4 over 64 blocks
  int b2 = bx - 44;
  const f32x4* wq4 = (const f32x4*)Wq;
#pragma unroll
  for (int it = 0; it < 4; ++it) {
    int i4 = it * 16384 + b2 * 256 + tid;
    f32x4 v = wq4[i4];
    u16x4 o;
    o[0] = f2bf(v[0]); o[1] = f2bf(v[1]); o[2] = f2bf(v[2]); o[3] = f2bf(v[3]);
    ((u16x4*)Wq_ws)[i4] = o;
  }
}

// K1: tile-transpose streaming copy. Block = (n, all c, 32 w).
// seq_len is a multiple of 128, tiles are 32-wide -> each tile is all-valid
// or all-invalid. Invalid: pure zero-fill (no reads). Valid: coalesced
// nontemporal in-read + out0 write (mask path gated by wave-uniform ballot),
// bf16 pre-mask values into padded LDS tile [c][w] only when the tile holds
// selected (masked/negative) slots; phase 2 emits A rows coalesced.
__global__ __launch_bounds__(256) void fused_copy_k(
    const float* __restrict__ in, const int* __restrict__ seq_len,
    const int* __restrict__ lookup, const float* __restrict__ mask_emb,
    float* __restrict__ out0, unsigned short* __restrict__ A_ws) {
  const int tid = threadIdx.x;
  const int bx = blockIdx.x;
  const int n = bx >> 7;                 // 16 n-lines
  const int w0 = (bx & 127) * 32;        // 128 w-tiles per line
  const int wl4 = (tid & 7) * 4;         // this thread's 4-w slot
  const int w = w0 + wl4;
  const int c0 = tid >> 3;               // 0..31
  const size_t rowbase = ((size_t)n << 21) + (size_t)w;   // element index
  f32x4* out4 = (f32x4*)out0;
  const int L = seq_len[n];

  if (w0 + 32 > L) {
    // fully-invalid tile: zero-fill out0, nothing else to do
    f32x4 z = {0.f, 0.f, 0.f, 0.f};
#pragma unroll
    for (int it = 0; it < 16; ++it) {
      int c = it * 32 + c0;
      __builtin_nontemporal_store(z, &out4[(rowbase + ((size_t)c << 12)) >> 2]);
    }
    return;
  }

  __shared__ unsigned short tile[CC * S_LDS];   // 36 KB
  __shared__ int g_s[32];
  if (tid < 32) g_s[tid] = lookup[n * WW + w0 + tid];

  const int4 g4 = *(const int4*)&lookup[n * WW + w];   // 16B aligned
  const int gg[4] = {g4.x, g4.y, g4.z, g4.w};
  bool lane_has_mask = ((unsigned)gg[0] < (unsigned)NMASK) |
                       ((unsigned)gg[1] < (unsigned)NMASK) |
                       ((unsigned)gg[2] < (unsigned)NMASK) |
                       ((unsigned)gg[3] < (unsigned)NMASK);
  bool lane_has_sel = (gg[0] >= 0) | (gg[1] >= 0) | (gg[2] >= 0) | (gg[3] >= 0);
  // every wave contains all 8 w4-groups (gg depends only on wl4), so the
  // ballot outcome is identical across the block's 4 waves -> block-uniform.
  bool has_mask = __ballot(lane_has_mask) != 0ull;
  bool has_sel = __ballot(lane_has_sel) != 0ull;   // superset of has_mask

  const f32x4* in4 = (const f32x4*)in;
#pragma unroll
  for (int it = 0; it < 16; ++it) {
    int c = it * 32 + c0;
    size_t i4 = (rowbase + ((size_t)c << 12)) >> 2;
    f32x4 v = __builtin_nontemporal_load(&in4[i4]);
    if (has_sel) {   // wave-uniform: stage pre-mask bf16 values for A emission
      u16x4 bf;
      bf[0] = f2bf(v[0]); bf[1] = f2bf(v[1]);
      bf[2] = f2bf(v[2]); bf[3] = f2bf(v[3]);
      *(u16x4*)&tile[c * S_LDS + wl4] = bf;
    }
    if (has_mask) {   // wave-uniform branch
      float o[4] = {v[0], v[1], v[2], v[3]};
#pragma unroll
      for (int k = 0; k < 4; ++k)
        if ((unsigned)gg[k] < (unsigned)NMASK)
          o[k] = mask_emb[(gg[k] & 3) * CC + c];
      v[0] = o[0]; v[1] = o[1]; v[2] = o[2]; v[3] = o[3];
    }
    __builtin_nontemporal_store(v, &out4[i4]);
  }
  if (!has_sel) return;    // block-uniform: no A rows from this tile
  __syncthreads();

  // Phase 2: coalesced A-row emission over selected slots only.
  const int lane = tid & 63;
  bool sel = (lane < 32) && (g_s[lane & 31] >= 0);
  unsigned smask = (unsigned)__ballot(sel);
  const int c2 = tid * 2;
  while (smask) {
    int wl = __builtin_ctz(smask);
    smask &= smask - 1;
    int g = g_s[wl];
    ushort2 val;
    val.x = tile[c2 * S_LDS + wl];
    val.y = tile[(c2 + 1) * S_LDS + wl];
    *(ushort2*)&A_ws[(size_t)g * CC + c2] = val;
  }
}

// K2: bf16 MFMA GEMM  out[m,f] = sum_c A[m,c]*Wq[f,c] + bq[f]
// M=11264, N=512, K=512.  64x128 block tile, 4 waves (2x2), 2x4 16x16
// frags/wave.  BK=64, double-buffered LDS (48 KB -> 3 blocks/CU; 704-block
// grid fully resident in one round), 2-phase pipeline: issue next K-tile's
// global_load_lds BEFORE the current tile's ds_read+MFMA; the single
// __syncthreads per K-tile (implicit vmcnt(0) drain) lands after the
// compute phase.  With only 2 buffers this drain is minimal-by-construction
// (R6's 4-buffer counted-vmcnt variant doubled barrier frequency and lost
// 2.3 us; R4's no-LDS variant exposed L2 latency and lost 21 us).
// LDS chunk-index XOR-swizzle on BOTH sides (rule #21).
__global__ __launch_bounds__(256) void gemm_k(
    const unsigned short* __restrict__ A, const unsigned short* __restrict__ B,
    const float* __restrict__ bq, float* __restrict__ out) {
  __shared__ unsigned short As[2][64 * 64];     // 2 x 8 KB
  __shared__ unsigned short Bs[2][128 * 64];    // 2 x 16 KB
  const int tid = threadIdx.x;
  const int lane = tid & 63;
  const int quad = lane >> 4;
  const int r16 = lane & 15;
  const int wv = tid >> 6;
  // bijective id -> (x, y): x = (id&7) + 8*(id>>5), y = (id>>3)&3
  const int id = blockIdx.x;
  const int xm = (id & 7) + ((id >> 5) << 3);   // [0, 176)
  const int yn = (id >> 3) & 3;                 // [0, 4)
  const int bm = xm * 64;
  const int bf = yn * 128;
  const int wm = (wv & 1) * 32;
  const int wf = (wv >> 1) * 64;
  const int wbase = tid & ~63;   // wave-uniform

  f32x4 acc[2][4];
#pragma unroll
  for (int mi = 0; mi < 2; ++mi)
#pragma unroll
    for (int fi = 0; fi < 4; ++fi)
      acc[mi][fi] = (f32x4){0.f, 0.f, 0.f, 0.f};

  // ---- staging: A tile 64x64 = 512 16B-chunks (2/thread),
  //               B tile 128x64 = 1024 chunks (4/thread).
  // LDS dest is linear (chunk ch at byte ch*16); the global source for
  // physical chunk p of row r fetches logical chunk (p ^ (r&7)).
#define STAGE_TILES(buf, k0)                                                  \
  do {                                                                        \
    _Pragma("unroll")                                                         \
    for (int it = 0; it < 2; ++it) {                                          \
      int ch = it * 256 + tid;                                                \
      int row = ch >> 3;                                                      \
      int l = (ch & 7) ^ (row & 7);                                           \
      gload_lds16(A + (size_t)(bm + row) * 512 + (k0) + l * 8,                \
                  &As[buf][(it * 256 + wbase) * 8]);                          \
    }                                                                         \
    _Pragma("unroll")                                                         \
    for (int it = 0; it < 4; ++it) {                                          \
      int ch = it * 256 + tid;                                                \
      int row = ch >> 3;                                                      \
      int l = (ch & 7) ^ (row & 7);                                           \
      gload_lds16(B + (size_t)(bf + row) * 512 + (k0) + l * 8,                \
                  &Bs[buf][(it * 256 + wbase) * 8]);                          \
    }                                                                         \
  } while (0)

  STAGE_TILES(0, 0);
  __syncthreads();           // drain prologue stage (vmcnt(0) implicit)

#pragma unroll
  for (int t = 0; t < 8; ++t) {
    const int cur = t & 1;
    if (t < 7) STAGE_TILES(cur ^ 1, (t + 1) * 64);   // in-flight during MFMA

    short8 a[2][2], b[4][2];
#pragma unroll
    for (int mi = 0; mi < 2; ++mi) {
      int row = wm + mi * 16 + r16;
      int base = row * 64;
      int rx = (row & 7) << 3;
#pragma unroll
      for (int ks = 0; ks < 2; ++ks)
        a[mi][ks] = *(const short8*)&As[cur][base + ((((ks * 4 + quad) << 3)) ^ rx)];
    }
#pragma unroll
    for (int fi = 0; fi < 4; ++fi) {
      int row = wf + fi * 16 + r16;
      int base = row * 64;
      int rx = (row & 7) << 3;
#pragma unroll
      for (int ks = 0; ks < 2; ++ks)
        b[fi][ks] = *(const short8*)&Bs[cur][base + ((((ks * 4 + quad) << 3)) ^ rx)];
    }
#pragma unroll
    for (int ks = 0; ks < 2; ++ks)
#pragma unroll
      for (int mi = 0; mi < 2; ++mi)
#pragma unroll
        for (int fi = 0; fi < 4; ++fi)
          acc[mi][fi] = __builtin_amdgcn_mfma_f32_16x16x32_bf16(
              a[mi][ks], b[fi][ks], acc[mi][fi], 0, 0, 0);
    if (t < 7) __syncthreads();   // WAR fence for next stage; none after t=7
  }
#undef STAGE_TILES

  // Epilogue: C/D layout col = lane&15 (f), row = quad*4 + reg (m).
#pragma unroll
  for (int fi = 0; fi < 4; ++fi) {
    int f = bf + wf + fi * 16 + r16;
    float bqv = bq[f];
#pragma unroll
    for (int mi = 0; mi < 2; ++mi) {
      int m0 = bm + wm + mi * 16 + quad * 4;
#pragma unroll
      for (int r = 0; r < 4; ++r)
        __builtin_nontemporal_store(acc[mi][fi][r] + bqv,
                                    &out[(size_t)(m0 + r) * 512 + f]);
    }
  }
}

extern "C" void kernel_launch(void* const* d_in, const int* in_sizes, int n_in,
                              void* d_out, int out_size, void* d_ws, size_t ws_size,
                              hipStream_t stream) {
  const float* inputs    = (const float*)d_in[0];
  const int*   seq_len   = (const int*)d_in[1];
  const int*   pack_idx  = (const int*)d_in[2];
  const int*   masked_idx= (const int*)d_in[3];
  const int*   neg_idx   = (const int*)d_in[4];
  const float* mask_emb  = (const float*)d_in[5];
  const float* Wq        = (const float*)d_in[6];
  const float* bq        = (const float*)d_in[7];
  float* out = (float*)d_out;
  char* ws = (char*)d_ws;
  int* lookup = (int*)(ws + WS_LOOKUP_OFF);
  unsigned short* wqb = (unsigned short*)(ws + WS_WQ_OFF);
  unsigned short* aws = (unsigned short*)(ws + WS_A_OFF);

  (void)hipMemsetAsync(lookup, 0xFF, NB * WW * sizeof(int), stream);  // all -1
  scatter_wq_k<<<108, 256, 0, stream>>>(pack_idx, masked_idx, neg_idx, lookup,
                                        Wq, wqb);
  fused_copy_k<<<2048, 256, 0, stream>>>(inputs, seq_len, lookup, mask_emb,
                                         out, aws);
  gemm_k<<<704, 256, 0, stream>>>(aws, wqb, bq, out + OUT0_ELEMS);
}